// Round 10
// baseline (617.241 us; speedup 1.0000x reference)
//
#include <hip/hip_runtime.h>
#include <hip/hip_cooperative_groups.h>

namespace cg = cooperative_groups;

#define N_NODES 50000
#define N_EDGES 800000
#define F_INPUT 256
#define HDIM 64
#define NCLS 10
#define NGRAPH 64

#define BSHIFT 7                 // 128 nodes per bucket
#define NBUCK 391                // ceil(50000/128)
#define SCAP 4096                // per-bucket stage/eadj capacity (mean 2046, 45 sigma)
#define PARTB 196                // edge-partition units in the fused part|gemm phase

typedef float f32x4v __attribute__((ext_vector_type(4)));
typedef short bf16x8 __attribute__((ext_vector_type(8)));

union B8U { uint4 q; bf16x8 v; };

// bf16 helpers: storage-only precision cut; all arithmetic stays fp32.
__device__ __forceinline__ float bflo(unsigned v) { return __uint_as_float(v << 16); }
__device__ __forceinline__ float bfhi(unsigned v) { return __uint_as_float(v & 0xFFFF0000u); }
__device__ __forceinline__ unsigned f2b2(float a, float b) {   // pack 2 floats -> 2 bf16 (RNE)
    unsigned x = __float_as_uint(a); x = (x + 0x7FFF + ((x >> 16) & 1)) >> 16;
    unsigned y = __float_as_uint(b); y = (y + 0x7FFF + ((y >> 16) & 1)) >> 16;
    return x | (y << 16);
}

// Dekker bf16 split of two floats -> packed hi dword + lo dword.
__device__ __forceinline__ void split2(float x0, float x1, unsigned& h, unsigned& l) {
    unsigned u0 = __float_as_uint(x0), u1 = __float_as_uint(x1);
    unsigned m0 = u0 & 0xFFFF0000u, m1 = u1 & 0xFFFF0000u;
    h = (u0 >> 16) | m1;
    float r0 = x0 - __uint_as_float(m0);
    float r1 = x1 - __uint_as_float(m1);
    l = (__float_as_uint(r0) >> 16) | (__float_as_uint(r1) & 0xFFFF0000u);
}

#define ADD8(b, u)                                    \
    b##0 += bflo(u.x); b##1 += bfhi(u.x);             \
    b##2 += bflo(u.y); b##3 += bfhi(u.y);             \
    b##4 += bflo(u.z); b##5 += bfhi(u.z);             \
    b##6 += bflo(u.w); b##7 += bfhi(u.w);

// 'wt' param name -- 'w' would be macro-substituted into 'u.w'.
#define FMA8(b, u, wt)                                                  \
    b##0 = fmaf(bflo(u.x), wt, b##0); b##1 = fmaf(bfhi(u.x), wt, b##1); \
    b##2 = fmaf(bflo(u.y), wt, b##2); b##3 = fmaf(bfhi(u.y), wt, b##3); \
    b##4 = fmaf(bflo(u.z), wt, b##4); b##5 = fmaf(bfhi(u.z), wt, b##5); \
    b##6 = fmaf(bflo(u.w), wt, b##6); b##7 = fmaf(bfhi(u.w), wt, b##7);

struct MegaP {
    const int* src; const int* dst; int E; int n;
    const float* x;
    const float* W1; const float* W2; const float* W3;
    const float* b1; const float* b2; const float* b3;
    const float* linW; const float* linb;
    const int* batch; float* out;
    unsigned short* hA; unsigned short* hB;
    float* dis; int* eadj; int* stage; int4* rng; int* bcnt; float* pooled;
    uint4* Bf1; uint4* Bf2; uint4* Bf3;
};

// Shared-memory union across phases (max 17.9 KB -> 4 blocks/CU fits easily).
union ShU {
    struct { int cnt[NBUCK]; int base[NBUCK]; } pt;                       // 3128 B
    struct { int cnt[128]; int loc[128]; int lcur[128]; int ebuf[SCAP]; } cs; // 17.9 KB
    uint4 rl[256];                                                        // 4 KB
    float sp[NGRAPH][HDIM];                                               // 16 KB
};

// ---------------- unit: prep (weight split + zero bcnt/pooled); 12 units --------------
static __device__ void prep_unit(int u, const MegaP& p) {
    int s = u * 256 + (int)threadIdx.x;   // 0..3071
    for (int j = s; j < NBUCK; j += 3072) p.bcnt[j] = 0;
    for (int j = s; j < NGRAPH * HDIM; j += 3072) p.pooled[j] = 0.f;
    const float* W; uint4* out; int local, KS;
    if (s < 2048)      { W = p.W1; out = p.Bf1; local = s;        KS = 8; }
    else if (s < 2560) { W = p.W2; out = p.Bf2; local = s - 2048; KS = 2; }
    else               { W = p.W3; out = p.Bf3; local = s - 2560; KS = 2; }
    const int lane = local & 63;
    const int t    = (local >> 6) & 3;
    const int ks   = local >> 8;
    const int kb   = ks * 32 + ((lane >> 4) << 3);
    const int col  = t * 16 + (lane & 15);
    unsigned h[4], l[4];
#pragma unroll
    for (int j = 0; j < 4; ++j) {
        float x0 = W[(size_t)(kb + 2 * j) * HDIM + col];
        float x1 = W[(size_t)(kb + 2 * j + 1) * HDIM + col];
        split2(x0, x1, h[j], l[j]);
    }
    out[(ks * 4 + t) * 64 + lane]        = make_uint4(h[0], h[1], h[2], h[3]);
    out[((KS + ks) * 4 + t) * 64 + lane] = make_uint4(l[0], l[1], l[2], l[3]);
}

// ---------------- unit: LDS-staged bucket partition; PARTB units ----------------------
static __device__ void part_unit(int u, const MegaP& p, ShU& sh) {
    const int tid = threadIdx.x;
    __syncthreads();                          // LDS reuse guard
    const int e0 = u * 4096;
    int pb[16], pv[16];
    for (int t = tid; t < NBUCK; t += 256) sh.pt.cnt[t] = 0;
    __syncthreads();
#pragma unroll
    for (int j = 0; j < 16; ++j) {
        int e = e0 + j * 256 + tid;
        if (e < p.E) {
            int s = p.src[e], d = p.dst[e];
            pb[j] = d >> BSHIFT;
            pv[j] = (s << BSHIFT) | (d & 127);
            atomicAdd(&sh.pt.cnt[pb[j]], 1);
        } else pb[j] = -1;
    }
    __syncthreads();
    for (int t = tid; t < NBUCK; t += 256) {
        int c = sh.pt.cnt[t];
        sh.pt.base[t] = c ? atomicAdd(&p.bcnt[t], c) : 0;
        sh.pt.cnt[t] = 0;
    }
    __syncthreads();
#pragma unroll
    for (int j = 0; j < 16; ++j) {
        if (pb[j] >= 0) {
            int r = sh.pt.base[pb[j]] + atomicAdd(&sh.pt.cnt[pb[j]], 1);
            if (r < SCAP) p.stage[pb[j] * SCAP + r] = pv[j];  // 45-sigma clamp
        }
    }
}

// ---------------- unit: layer-1 GEMM (fp32 A, split-bf16 3-pass), unscaled ------------
static __device__ void gemm1_unit(int u, const MegaP& p) {
    const int tid = threadIdx.x;
    const int ln  = tid & 63;
    const int wv  = tid >> 6;
    const int m   = ln & 15;
    const int kg  = ln >> 4;
    const int n   = p.n;
    const int ktn = 8;
    const int grow = u * 64 + wv * 16 + m;
    const float* ar = p.x + (size_t)min(grow, n - 1) * F_INPUT + kg * 8;

    f32x4v acc[4];
#pragma unroll
    for (int t = 0; t < 4; ++t)
#pragma unroll
        for (int j = 0; j < 4; ++j) acc[t][j] = 0.0f;

    float4 c0 = *(const float4*)(ar);
    float4 c1 = *(const float4*)(ar + 4);

    for (int ks = 0; ks < ktn; ++ks) {
        const int kn = (ks + 1 < ktn) ? (ks + 1) * 32 : 0;   // prefetch rotation
        float4 p0 = *(const float4*)(ar + kn);
        float4 p1 = *(const float4*)(ar + kn + 4);

        const uint4* bp = p.Bf1 + (size_t)ks * 256 + ln;          // hi plane
        const uint4* bq = p.Bf1 + (size_t)(ktn + ks) * 256 + ln;  // lo plane
        B8U bh0, bh1, bh2, bh3, bl0, bl1, bl2, bl3;
        bh0.q = bp[0];   bh1.q = bp[64];  bh2.q = bp[128]; bh3.q = bp[192];
        bl0.q = bq[0];   bl1.q = bq[64];  bl2.q = bq[128]; bl3.q = bq[192];

        B8U ah, al;
        split2(c0.x, c0.y, ah.q.x, al.q.x);
        split2(c0.z, c0.w, ah.q.y, al.q.y);
        split2(c1.x, c1.y, ah.q.z, al.q.z);
        split2(c1.z, c1.w, ah.q.w, al.q.w);

        acc[0] = __builtin_amdgcn_mfma_f32_16x16x32_bf16(bh0.v, ah.v, acc[0], 0, 0, 0);
        acc[1] = __builtin_amdgcn_mfma_f32_16x16x32_bf16(bh1.v, ah.v, acc[1], 0, 0, 0);
        acc[2] = __builtin_amdgcn_mfma_f32_16x16x32_bf16(bh2.v, ah.v, acc[2], 0, 0, 0);
        acc[3] = __builtin_amdgcn_mfma_f32_16x16x32_bf16(bh3.v, ah.v, acc[3], 0, 0, 0);
        acc[0] = __builtin_amdgcn_mfma_f32_16x16x32_bf16(bl0.v, ah.v, acc[0], 0, 0, 0);
        acc[1] = __builtin_amdgcn_mfma_f32_16x16x32_bf16(bl1.v, ah.v, acc[1], 0, 0, 0);
        acc[2] = __builtin_amdgcn_mfma_f32_16x16x32_bf16(bl2.v, ah.v, acc[2], 0, 0, 0);
        acc[3] = __builtin_amdgcn_mfma_f32_16x16x32_bf16(bl3.v, ah.v, acc[3], 0, 0, 0);
        acc[0] = __builtin_amdgcn_mfma_f32_16x16x32_bf16(bh0.v, al.v, acc[0], 0, 0, 0);
        acc[1] = __builtin_amdgcn_mfma_f32_16x16x32_bf16(bh1.v, al.v, acc[1], 0, 0, 0);
        acc[2] = __builtin_amdgcn_mfma_f32_16x16x32_bf16(bh2.v, al.v, acc[2], 0, 0, 0);
        acc[3] = __builtin_amdgcn_mfma_f32_16x16x32_bf16(bh3.v, al.v, acc[3], 0, 0, 0);

        c0 = p0; c1 = p1;
    }

    if (grow < n) {
#pragma unroll
        for (int t = 0; t < 4; ++t) {
            uint2 pk;
            pk.x = f2b2(acc[t][0], acc[t][1]);
            pk.y = f2b2(acc[t][2], acc[t][3]);
            *(uint2*)(p.hA + (size_t)grow * HDIM + t * 16 + kg * 4) = pk;
        }
    }
}

// ---------------- unit: degree + scan + counting sort; NBUCK units --------------------
static __device__ void csr_unit(int u, const MegaP& p, ShU& sh) {
    const int tid = threadIdx.x;
    __syncthreads();                          // LDS reuse guard
    const int n0 = u << BSHIFT;
    const int nn = min(128, p.n - n0);
    const int sb = u * SCAP;
    const int len = min(p.bcnt[u], SCAP);
    if (tid < 128) sh.cs.cnt[tid] = 0;
    __syncthreads();
    for (int j = tid; j < len; j += 256) atomicAdd(&sh.cs.cnt[p.stage[sb + j] & 127], 1);
    __syncthreads();
    if (tid < 128) sh.cs.loc[tid] = sh.cs.cnt[tid];
    __syncthreads();
    for (int d = 1; d < 128; d <<= 1) {       // Hillis-Steele inclusive scan
        int x = 0;
        if (tid < 128 && tid >= d) x = sh.cs.loc[tid - d];
        __syncthreads();
        if (tid < 128) sh.cs.loc[tid] += x;
        __syncthreads();
    }
    if (tid < 128) {
        int ex = sh.cs.loc[tid] - sh.cs.cnt[tid];          // exclusive
        if (tid < nn) {
            int dg = sh.cs.cnt[tid];
            float di = rsqrtf((float)(dg + 1));
            p.dis[n0 + tid] = di;
            p.rng[n0 + tid] = make_int4(sb + ex, sb + ex + dg, __float_as_int(di), 0);
        }
        sh.cs.lcur[tid] = ex;
    }
    __syncthreads();
    for (int j = tid; j < len; j += 256) {
        int pv = p.stage[sb + j];
        int rk = atomicAdd(&sh.cs.lcur[pv & 127], 1);
        sh.cs.ebuf[rk] = pv >> BSHIFT;
    }
    __syncthreads();
    for (int j = tid; j < len; j += 256) p.eadj[sb + j] = sh.cs.ebuf[j];  // linear write
}

// ---------------- shared GEMM tail for the fused gather+GEMM units --------------------
static __device__ __forceinline__ void fgg_gemm_tail(const MegaP& p, ShU& sh,
                                                     const uint4* Bf,
                                                     unsigned short* out, int i0) {
    const int tid = threadIdx.x;
    const int ln = tid & 63;
    const int wv = tid >> 6;
    const int m  = ln & 15;
    const int kg = ln >> 4;
    const int row = (wv >> 1) * 16 + m;
    const int ct0 = (wv & 1) * 2;
    f32x4v acc0, acc1;
#pragma unroll
    for (int j = 0; j < 4; ++j) { acc0[j] = 0.f; acc1[j] = 0.f; }
#pragma unroll
    for (int ks = 0; ks < 2; ++ks) {
        B8U af;
        af.q = sh.rl[row * 8 + ((ks * 4 + kg) ^ (row & 7))];
        const uint4* bp = Bf + ks * 256 + ln;
        const uint4* bq = Bf + (2 + ks) * 256 + ln;
        B8U bh0, bh1, bl0, bl1;
        bh0.q = bp[ct0 * 64]; bh1.q = bp[(ct0 + 1) * 64];
        bl0.q = bq[ct0 * 64]; bl1.q = bq[(ct0 + 1) * 64];
        acc0 = __builtin_amdgcn_mfma_f32_16x16x32_bf16(bh0.v, af.v, acc0, 0, 0, 0);
        acc1 = __builtin_amdgcn_mfma_f32_16x16x32_bf16(bh1.v, af.v, acc1, 0, 0, 0);
        acc0 = __builtin_amdgcn_mfma_f32_16x16x32_bf16(bl0.v, af.v, acc0, 0, 0, 0);
        acc1 = __builtin_amdgcn_mfma_f32_16x16x32_bf16(bl1.v, af.v, acc1, 0, 0, 0);
    }
    const int grow = i0 + row;
    if (grow < p.n) {
        const float di = p.dis[grow];
        uint2 pk;
        pk.x = f2b2(acc0[0] * di, acc0[1] * di);
        pk.y = f2b2(acc0[2] * di, acc0[3] * di);
        *(uint2*)(out + (size_t)grow * HDIM + ct0 * 16 + kg * 4) = pk;
        pk.x = f2b2(acc1[0] * di, acc1[1] * di);
        pk.y = f2b2(acc1[2] * di, acc1[3] * di);
        *(uint2*)(out + (size_t)grow * HDIM + (ct0 + 1) * 16 + kg * 4) = pk;
    }
}

// ---------------- unit: fgg1 = weighted gather (unscaled hA) + GEMM(W2) -> hB ---------
static __device__ void fggw_unit(int u, const MegaP& p, ShU& sh) {
    const int tid = threadIdx.x;
    __syncthreads();                          // LDS reuse guard
    const int i0 = u * 32;
    const int node = tid >> 3;
    const int l8 = tid & 7;
    const int i = i0 + node;
    uint4 o = make_uint4(0u, 0u, 0u, 0u);
    if (i < p.n) {
        const int q = l8 * 8;
        const int4 r = p.rng[i];
        int e = r.x; const int e1 = r.y;
        const float di = __int_as_float(r.z);
        float a0 = 0.f, a1 = 0.f, a2 = 0.f, a3 = 0.f, a4 = 0.f, a5 = 0.f, a6 = 0.f, a7 = 0.f;
        float g0 = 0.f, g1 = 0.f, g2 = 0.f, g3 = 0.f, g4 = 0.f, g5 = 0.f, g6 = 0.f, g7 = 0.f;
#pragma unroll 2
        for (; e + 3 < e1; e += 4) {
            int s0 = p.eadj[e];
            int s1 = p.eadj[e + 1];
            int s2 = p.eadj[e + 2];
            int s3 = p.eadj[e + 3];
            uint4 u0 = *(const uint4*)(p.hA + (size_t)s0 * HDIM + q);
            uint4 u1 = *(const uint4*)(p.hA + (size_t)s1 * HDIM + q);
            uint4 u2 = *(const uint4*)(p.hA + (size_t)s2 * HDIM + q);
            uint4 u3 = *(const uint4*)(p.hA + (size_t)s3 * HDIM + q);
            float w0 = p.dis[s0] * di;
            float w1 = p.dis[s1] * di;
            float w2 = p.dis[s2] * di;
            float w3 = p.dis[s3] * di;
            FMA8(a, u0, w0)
            FMA8(g, u1, w1)
            FMA8(a, u2, w2)
            FMA8(g, u3, w3)
        }
        for (; e < e1; ++e) {
            int s0 = p.eadj[e];
            uint4 u0 = *(const uint4*)(p.hA + (size_t)s0 * HDIM + q);
            float w0 = p.dis[s0] * di;
            FMA8(a, u0, w0)
        }
        uint4 us = *(const uint4*)(p.hA + (size_t)i * HDIM + q);   // self, weight di^2
        float sn = di * di;
        FMA8(a, us, sn)
        a0 += g0; a1 += g1; a2 += g2; a3 += g3;
        a4 += g4; a5 += g5; a6 += g6; a7 += g7;
        float4 bl = *(const float4*)(p.b1 + q);
        float4 bh = *(const float4*)(p.b1 + q + 4);
        a0 = fmaxf(a0 + bl.x, 0.f); a1 = fmaxf(a1 + bl.y, 0.f);
        a2 = fmaxf(a2 + bl.z, 0.f); a3 = fmaxf(a3 + bl.w, 0.f);
        a4 = fmaxf(a4 + bh.x, 0.f); a5 = fmaxf(a5 + bh.y, 0.f);
        a6 = fmaxf(a6 + bh.z, 0.f); a7 = fmaxf(a7 + bh.w, 0.f);
        o.x = f2b2(a0, a1); o.y = f2b2(a2, a3);
        o.z = f2b2(a4, a5); o.w = f2b2(a6, a7);
    }
    sh.rl[node * 8 + (l8 ^ (node & 7))] = o;   // swizzle: kills col-read bank conflict
    __syncthreads();
    fgg_gemm_tail(p, sh, p.Bf2, p.hB, i0);
}

// ---------------- unit: fgg2 = pure-add gather (pre-scaled hB) + GEMM(W3) -> hA -------
static __device__ void fgg_unit(int u, const MegaP& p, ShU& sh) {
    const int tid = threadIdx.x;
    __syncthreads();                          // LDS reuse guard
    const int i0 = u * 32;
    const int node = tid >> 3;
    const int l8 = tid & 7;
    const int i = i0 + node;
    uint4 o = make_uint4(0u, 0u, 0u, 0u);
    if (i < p.n) {
        const int q = l8 * 8;
        const int4 r = p.rng[i];
        int e = r.x; const int e1 = r.y;
        const float di = __int_as_float(r.z);
        float a0 = 0.f, a1 = 0.f, a2 = 0.f, a3 = 0.f, a4 = 0.f, a5 = 0.f, a6 = 0.f, a7 = 0.f;
        float g0 = 0.f, g1 = 0.f, g2 = 0.f, g3 = 0.f, g4 = 0.f, g5 = 0.f, g6 = 0.f, g7 = 0.f;
#pragma unroll 2
        for (; e + 3 < e1; e += 4) {
            int s0 = p.eadj[e];
            int s1 = p.eadj[e + 1];
            int s2 = p.eadj[e + 2];
            int s3 = p.eadj[e + 3];
            uint4 u0 = *(const uint4*)(p.hB + (size_t)s0 * HDIM + q);
            uint4 u1 = *(const uint4*)(p.hB + (size_t)s1 * HDIM + q);
            uint4 u2 = *(const uint4*)(p.hB + (size_t)s2 * HDIM + q);
            uint4 u3 = *(const uint4*)(p.hB + (size_t)s3 * HDIM + q);
            ADD8(a, u0)
            ADD8(g, u1)
            ADD8(a, u2)
            ADD8(g, u3)
        }
        for (; e < e1; ++e) {
            int s0 = p.eadj[e];
            uint4 u0 = *(const uint4*)(p.hB + (size_t)s0 * HDIM + q);
            ADD8(a, u0)
        }
        uint4 us = *(const uint4*)(p.hB + (size_t)i * HDIM + q);
        ADD8(a, us)
        a0 += g0; a1 += g1; a2 += g2; a3 += g3;
        a4 += g4; a5 += g5; a6 += g6; a7 += g7;
        float4 bl = *(const float4*)(p.b2 + q);
        float4 bh = *(const float4*)(p.b2 + q + 4);
        a0 = fmaxf(fmaf(a0, di, bl.x), 0.f);
        a1 = fmaxf(fmaf(a1, di, bl.y), 0.f);
        a2 = fmaxf(fmaf(a2, di, bl.z), 0.f);
        a3 = fmaxf(fmaf(a3, di, bl.w), 0.f);
        a4 = fmaxf(fmaf(a4, di, bh.x), 0.f);
        a5 = fmaxf(fmaf(a5, di, bh.y), 0.f);
        a6 = fmaxf(fmaf(a6, di, bh.z), 0.f);
        a7 = fmaxf(fmaf(a7, di, bh.w), 0.f);
        o.x = f2b2(a0, a1); o.y = f2b2(a2, a3);
        o.z = f2b2(a4, a5); o.w = f2b2(a6, a7);
    }
    sh.rl[node * 8 + (l8 ^ (node & 7))] = o;
    __syncthreads();
    fgg_gemm_tail(p, sh, p.Bf3, p.hA, i0);
}

// ---------------- unit: layer-3 gather + mean-pool accumulate -------------------------
static __device__ void pool_unit(int u, const MegaP& p, ShU& sh) {
    const int tid = threadIdx.x;
    __syncthreads();                          // LDS reuse guard
    int t = u * 256 + tid;
    int i = t >> 3;
    const bool valid = (i < p.n);
    int q = (t & 7) * 8;
    const int i0 = (u * 256) >> 3;
    const int i1 = min(i0 + 32, p.n);
    const int gmin = p.batch[min(i0, p.n - 1)];
    const int gmax = p.batch[i1 - 1];
    for (int j = tid; j < NGRAPH * HDIM; j += 256) ((float*)sh.sp)[j] = 0.f;
    __syncthreads();
    if (valid) {
        const int4 r = p.rng[i];
        int e = r.x; const int e1 = r.y;
        const float di = __int_as_float(r.z);
        float a0 = 0.f, a1 = 0.f, a2 = 0.f, a3 = 0.f, a4 = 0.f, a5 = 0.f, a6 = 0.f, a7 = 0.f;
        float g0 = 0.f, g1 = 0.f, g2 = 0.f, g3 = 0.f, g4 = 0.f, g5 = 0.f, g6 = 0.f, g7 = 0.f;
#pragma unroll 2
        for (; e + 3 < e1; e += 4) {
            int s0 = p.eadj[e];
            int s1 = p.eadj[e + 1];
            int s2 = p.eadj[e + 2];
            int s3 = p.eadj[e + 3];
            uint4 u0 = *(const uint4*)(p.hA + (size_t)s0 * HDIM + q);
            uint4 u1 = *(const uint4*)(p.hA + (size_t)s1 * HDIM + q);
            uint4 u2 = *(const uint4*)(p.hA + (size_t)s2 * HDIM + q);
            uint4 u3 = *(const uint4*)(p.hA + (size_t)s3 * HDIM + q);
            ADD8(a, u0)
            ADD8(g, u1)
            ADD8(a, u2)
            ADD8(g, u3)
        }
        for (; e < e1; ++e) {
            int s0 = p.eadj[e];
            uint4 u0 = *(const uint4*)(p.hA + (size_t)s0 * HDIM + q);
            ADD8(a, u0)
        }
        uint4 us = *(const uint4*)(p.hA + (size_t)i * HDIM + q);
        ADD8(a, us)
        a0 += g0; a1 += g1; a2 += g2; a3 += g3;
        a4 += g4; a5 += g5; a6 += g6; a7 += g7;
        float4 bl = *(const float4*)(p.b3 + q);
        float4 bh = *(const float4*)(p.b3 + q + 4);
        a0 = fmaxf(fmaf(a0, di, bl.x), 0.f);
        a1 = fmaxf(fmaf(a1, di, bl.y), 0.f);
        a2 = fmaxf(fmaf(a2, di, bl.z), 0.f);
        a3 = fmaxf(fmaf(a3, di, bl.w), 0.f);
        a4 = fmaxf(fmaf(a4, di, bh.x), 0.f);
        a5 = fmaxf(fmaf(a5, di, bh.y), 0.f);
        a6 = fmaxf(fmaf(a6, di, bh.z), 0.f);
        a7 = fmaxf(fmaf(a7, di, bh.w), 0.f);
        int g = p.batch[i];
        atomicAdd(&sh.sp[g][q + 0], a0); atomicAdd(&sh.sp[g][q + 1], a1);
        atomicAdd(&sh.sp[g][q + 2], a2); atomicAdd(&sh.sp[g][q + 3], a3);
        atomicAdd(&sh.sp[g][q + 4], a4); atomicAdd(&sh.sp[g][q + 5], a5);
        atomicAdd(&sh.sp[g][q + 6], a6); atomicAdd(&sh.sp[g][q + 7], a7);
    }
    __syncthreads();
    int rows = gmax - gmin + 1;
    for (int j = tid; j < rows * HDIM; j += 256) {
        int r = j >> 6, c = j & 63;
        float v = sh.sp[gmin + r][c];
        if (v != 0.f) atomicAdd(&p.pooled[(gmin + r) * HDIM + c], v);
    }
}

// ---------------- unit: mean + linear head (1 unit, 256 threads loop) -----------------
static __device__ void head_unit(const MegaP& p) {
    for (int tt = threadIdx.x; tt < NGRAPH * NCLS; tt += 256) {
        int g = tt / NCLS;
        int c = tt - g * NCLS;
        int lo = 0, hi = p.n;
        while (lo < hi) { int m2 = (lo + hi) >> 1; if (p.batch[m2] < g) lo = m2 + 1; else hi = m2; }
        int s = lo;
        lo = 0; hi = p.n;
        while (lo < hi) { int m2 = (lo + hi) >> 1; if (p.batch[m2] < g + 1) lo = m2 + 1; else hi = m2; }
        float inv = 1.0f / fmaxf((float)(lo - s), 1.0f);
        float acc = p.linb[c];
#pragma unroll
        for (int k = 0; k < HDIM; ++k)
            acc = fmaf(p.pooled[g * HDIM + k] * inv, p.linW[k * NCLS + c], acc);
        p.out[g * NCLS + c] = acc;
    }
}

// ---------------- cooperative mega-kernel: all 7 phases, 6 grid syncs -----------------
__global__ __launch_bounds__(256, 4) void k_mega(MegaP p) {
    __shared__ ShU sh;
    cg::grid_group grid = cg::this_grid();
    const int gb = (p.n + 63) / 64;
    const int nF = (p.n + 31) / 32;
    for (int u = blockIdx.x; u < 12; u += gridDim.x) prep_unit(u, p);
    grid.sync();
    for (int u = blockIdx.x; u < PARTB + gb; u += gridDim.x) {
        if (u < PARTB) part_unit(u, p, sh);
        else           gemm1_unit(u - PARTB, p);
    }
    grid.sync();
    for (int u = blockIdx.x; u < NBUCK; u += gridDim.x) csr_unit(u, p, sh);
    grid.sync();
    for (int u = blockIdx.x; u < nF; u += gridDim.x) fggw_unit(u, p, sh);
    grid.sync();
    for (int u = blockIdx.x; u < nF; u += gridDim.x) fgg_unit(u, p, sh);
    grid.sync();
    for (int u = blockIdx.x; u < nF; u += gridDim.x) pool_unit(u, p, sh);
    grid.sync();
    if (blockIdx.x == 0) head_unit(p);
}

// ---------------- standalone fallback kernels (same units, 7 dispatches) --------------
__global__ __launch_bounds__(256) void k_prepS(MegaP p) { prep_unit(blockIdx.x, p); }
__global__ __launch_bounds__(256) void k_pgS(MegaP p) {
    __shared__ ShU sh;
    if ((int)blockIdx.x < PARTB) part_unit(blockIdx.x, p, sh);
    else                         gemm1_unit(blockIdx.x - PARTB, p);
}
__global__ __launch_bounds__(256) void k_csrS(MegaP p)  { __shared__ ShU sh; csr_unit(blockIdx.x, p, sh); }
__global__ __launch_bounds__(256) void k_fggwS(MegaP p) { __shared__ ShU sh; fggw_unit(blockIdx.x, p, sh); }
__global__ __launch_bounds__(256) void k_fggS(MegaP p)  { __shared__ ShU sh; fgg_unit(blockIdx.x, p, sh); }
__global__ __launch_bounds__(256) void k_poolS(MegaP p) { __shared__ ShU sh; pool_unit(blockIdx.x, p, sh); }
__global__ __launch_bounds__(256) void k_headS(MegaP p) { head_unit(p); }

extern "C" void kernel_launch(void* const* d_in, const int* in_sizes, int n_in,
                              void* d_out, int out_size, void* d_ws, size_t ws_size,
                              hipStream_t stream) {
    (void)in_sizes; (void)n_in; (void)out_size; (void)ws_size;
    MegaP p;
    p.x    = (const float*)d_in[0];
    const int* ei = (const int*)d_in[1];
    p.batch = (const int*)d_in[2];
    p.W1 = (const float*)d_in[3];  p.b1 = (const float*)d_in[4];
    p.W2 = (const float*)d_in[5];  p.b2 = (const float*)d_in[6];
    p.W3 = (const float*)d_in[7];  p.b3 = (const float*)d_in[8];
    p.linW = (const float*)d_in[9]; p.linb = (const float*)d_in[10];
    p.out = (float*)d_out;
    p.E = N_EDGES;
    p.n = N_NODES;
    p.src = ei;
    p.dst = ei + N_EDGES;

    char* ws = (char*)d_ws;
    p.hA   = (unsigned short*)ws; ws += (size_t)N_NODES * HDIM * 2;
    p.hB   = (unsigned short*)ws; ws += (size_t)N_NODES * HDIM * 2;
    p.dis  = (float*)ws;          ws += (size_t)N_NODES * 4;
    p.eadj = (int*)ws;            ws += (size_t)NBUCK * SCAP * 4;
    p.stage= (int*)ws;            ws += (size_t)NBUCK * SCAP * 4;
    p.rng  = (int4*)ws;           ws += (size_t)N_NODES * 16;
    p.bcnt = (int*)ws;            ws += ((size_t)NBUCK * 4 + 15) & ~(size_t)15;
    p.pooled = (float*)ws;        ws += (size_t)NGRAPH * HDIM * 4;
    p.Bf1  = (uint4*)ws;          ws += (size_t)2 * 8 * 4 * 64 * 16;   // 64 KB
    p.Bf2  = (uint4*)ws;          ws += (size_t)2 * 2 * 4 * 64 * 16;   // 16 KB
    p.Bf3  = (uint4*)ws;          ws += (size_t)2 * 2 * 4 * 64 * 16;   // 16 KB

    const int gb = (N_NODES + 63) / 64;    // 782
    const int nF = (N_NODES + 31) / 32;    // 1563

    // Cooperative grid size: co-resident blocks only (query once).
    static int coopGrid = -1;
    if (coopGrid < 0) {
        int occ = 0;
        hipError_t oe = hipOccupancyMaxActiveBlocksPerMultiprocessor(
            &occ, reinterpret_cast<const void*>(k_mega), 256, 0);
        if (oe != hipSuccess || occ < 1) coopGrid = 0;       // disable coop path
        else {
            long g = (long)occ * 256;                         // 256 CUs on MI355X
            if (g > nF) g = nF;
            coopGrid = (int)g;
        }
    }

    bool done = false;
    if (coopGrid > 0) {
        void* args[] = { (void*)&p };
        hipError_t le = hipLaunchCooperativeKernel(
            reinterpret_cast<const void*>(k_mega),
            dim3(coopGrid), dim3(256), args, 0, stream);
        done = (le == hipSuccess);
    }
    if (!done) {
        // fallback: proven 7-dispatch pipeline with identical unit code
        k_prepS<<<12, 256, 0, stream>>>(p);
        k_pgS<<<PARTB + gb, 256, 0, stream>>>(p);
        k_csrS<<<NBUCK, 256, 0, stream>>>(p);
        k_fggwS<<<nF, 256, 0, stream>>>(p);
        k_fggS<<<nF, 256, 0, stream>>>(p);
        k_poolS<<<nF, 256, 0, stream>>>(p);
        k_headS<<<1, 256, 0, stream>>>(p);
    }
}

// Round 11
// 216.351 us; speedup vs baseline: 2.8530x; 2.8530x over previous
//
#include <hip/hip_runtime.h>

#define N_NODES 50000
#define N_EDGES 800000
#define F_INPUT 256
#define HDIM 64
#define NCLS 10
#define NGRAPH 64

#define BSHIFT 7                 // 128 nodes per bucket
#define NBUCK 391                // ceil(50000/128)
#define SCAP 4096                // per-bucket stage/eadj capacity (mean 2046, 45 sigma)
#define PARTB 196                // edge-partition blocks in the fused part|gemm dispatch

typedef float f32x4v __attribute__((ext_vector_type(4)));
typedef short bf16x8 __attribute__((ext_vector_type(8)));

union B8U { uint4 q; bf16x8 v; };

// bf16 helpers: storage-only precision cut; all arithmetic stays fp32.
__device__ __forceinline__ float bflo(unsigned v) { return __uint_as_float(v << 16); }
__device__ __forceinline__ float bfhi(unsigned v) { return __uint_as_float(v & 0xFFFF0000u); }
__device__ __forceinline__ unsigned f2b2(float a, float b) {   // pack 2 floats -> 2 bf16 (RNE)
    unsigned x = __float_as_uint(a); x = (x + 0x7FFF + ((x >> 16) & 1)) >> 16;
    unsigned y = __float_as_uint(b); y = (y + 0x7FFF + ((y >> 16) & 1)) >> 16;
    return x | (y << 16);
}

// Dekker bf16 split of two floats -> packed hi dword + lo dword.
__device__ __forceinline__ void split2(float x0, float x1, unsigned& h, unsigned& l) {
    unsigned u0 = __float_as_uint(x0), u1 = __float_as_uint(x1);
    unsigned m0 = u0 & 0xFFFF0000u, m1 = u1 & 0xFFFF0000u;
    h = (u0 >> 16) | m1;
    float r0 = x0 - __uint_as_float(m0);
    float r1 = x1 - __uint_as_float(m1);
    l = (__float_as_uint(r0) >> 16) | (__float_as_uint(r1) & 0xFFFF0000u);
}

// 8-feature accumulate of a bf16x8 row (pre-scaled rows, weight 1).
#define ADD8(b, u)                                    \
    b##0 += bflo(u.x); b##1 += bfhi(u.x);             \
    b##2 += bflo(u.y); b##3 += bfhi(u.y);             \
    b##4 += bflo(u.z); b##5 += bfhi(u.z);             \
    b##6 += bflo(u.w); b##7 += bfhi(u.w);

// 8-feature weighted FMA ('wt' param name -- 'w' would collide with u.w).
#define FMA8(b, u, wt)                                                  \
    b##0 = fmaf(bflo(u.x), wt, b##0); b##1 = fmaf(bfhi(u.x), wt, b##1); \
    b##2 = fmaf(bflo(u.y), wt, b##2); b##3 = fmaf(bfhi(u.y), wt, b##3); \
    b##4 = fmaf(bflo(u.z), wt, b##4); b##5 = fmaf(bfhi(u.z), wt, b##5); \
    b##6 = fmaf(bflo(u.w), wt, b##6); b##7 = fmaf(bfhi(u.w), wt, b##7);

// ---------------- prep: weight split + zero bcnt/pooled (one dispatch) ----------------
__global__ __launch_bounds__(256) void k_prepZ(const float* __restrict__ W1,
                                               const float* __restrict__ W2,
                                               const float* __restrict__ W3,
                                               uint4* __restrict__ Bf1,
                                               uint4* __restrict__ Bf2,
                                               uint4* __restrict__ Bf3,
                                               int* __restrict__ bcnt,
                                               float* __restrict__ pooled) {
    int s = blockIdx.x * 256 + threadIdx.x;   // 0..3071
    for (int j = s; j < NBUCK; j += 3072) bcnt[j] = 0;
    for (int j = s; j < NGRAPH * HDIM; j += 3072) pooled[j] = 0.f;
    const float* W; uint4* out; int local, KS;
    if (s < 2048)      { W = W1; out = Bf1; local = s;        KS = 8; }
    else if (s < 2560) { W = W2; out = Bf2; local = s - 2048; KS = 2; }
    else               { W = W3; out = Bf3; local = s - 2560; KS = 2; }
    const int lane = local & 63;
    const int t    = (local >> 6) & 3;
    const int ks   = local >> 8;
    const int kb   = ks * 32 + ((lane >> 4) << 3);
    const int col  = t * 16 + (lane & 15);
    unsigned h[4], l[4];
#pragma unroll
    for (int j = 0; j < 4; ++j) {
        float x0 = W[(size_t)(kb + 2 * j) * HDIM + col];
        float x1 = W[(size_t)(kb + 2 * j + 1) * HDIM + col];
        split2(x0, x1, h[j], l[j]);
    }
    out[(ks * 4 + t) * 64 + lane]          = make_uint4(h[0], h[1], h[2], h[3]);
    out[((KS + ks) * 4 + t) * 64 + lane]   = make_uint4(l[0], l[1], l[2], l[3]);
}

// ---------------- fused: edge partition (blocks [0,PARTB)) ∪ layer-1 GEMM -------------
// gemm1 does not need dis (unscaled h1; normalization lives in fgg1's gather),
// so it is independent of part/csr and shares this dispatch with part.
__global__ __launch_bounds__(256) void k_pg(const int* __restrict__ src,
                                            const int* __restrict__ dst,
                                            int* __restrict__ bcnt,
                                            int* __restrict__ stage, int E,
                                            const float* __restrict__ A,
                                            const uint4* __restrict__ Bf,
                                            unsigned short* __restrict__ C,
                                            int n, int lda, int ktn) {
    __shared__ int cnt[NBUCK];
    __shared__ int base[NBUCK];
    const int tid = threadIdx.x;
    if ((int)blockIdx.x < PARTB) {
        const int e0 = blockIdx.x * 4096;
        int pb[16], pv[16];
        for (int t = tid; t < NBUCK; t += 256) cnt[t] = 0;
        __syncthreads();
#pragma unroll
        for (int j = 0; j < 16; ++j) {
            int e = e0 + j * 256 + tid;
            if (e < E) {
                int s = src[e], d = dst[e];
                pb[j] = d >> BSHIFT;
                pv[j] = (s << BSHIFT) | (d & 127);
                atomicAdd(&cnt[pb[j]], 1);
            } else pb[j] = -1;
        }
        __syncthreads();
        for (int t = tid; t < NBUCK; t += 256) {
            int c = cnt[t];
            base[t] = c ? atomicAdd(&bcnt[t], c) : 0;
            cnt[t] = 0;
        }
        __syncthreads();
#pragma unroll
        for (int j = 0; j < 16; ++j) {
            if (pb[j] >= 0) {
                int r = base[pb[j]] + atomicAdd(&cnt[pb[j]], 1);
                if (r < SCAP) stage[pb[j] * SCAP + r] = pv[j];  // 45-sigma clamp
            }
        }
        return;
    }
    // ---- layer-1 GEMM (fp32 A, split-bf16 3-pass), UNSCALED bf16 output ----
    const int ln  = tid & 63;
    const int wv  = tid >> 6;
    const int m   = ln & 15;
    const int kg  = ln >> 4;
    const int grow = (blockIdx.x - PARTB) * 64 + wv * 16 + m;
    const float* ar = A + (size_t)min(grow, n - 1) * lda + kg * 8;

    f32x4v acc[4];
#pragma unroll
    for (int t = 0; t < 4; ++t)
#pragma unroll
        for (int j = 0; j < 4; ++j) acc[t][j] = 0.0f;

    float4 c0 = *(const float4*)(ar);
    float4 c1 = *(const float4*)(ar + 4);

    for (int ks = 0; ks < ktn; ++ks) {
        const int kn = (ks + 1 < ktn) ? (ks + 1) * 32 : 0;   // prefetch rotation
        float4 p0 = *(const float4*)(ar + kn);
        float4 p1 = *(const float4*)(ar + kn + 4);

        const uint4* bp = Bf + (size_t)ks * 256 + ln;          // hi plane
        const uint4* bq = Bf + (size_t)(ktn + ks) * 256 + ln;  // lo plane
        B8U bh0, bh1, bh2, bh3, bl0, bl1, bl2, bl3;
        bh0.q = bp[0];   bh1.q = bp[64];  bh2.q = bp[128]; bh3.q = bp[192];
        bl0.q = bq[0];   bl1.q = bq[64];  bl2.q = bq[128]; bl3.q = bq[192];

        B8U ah, al;
        split2(c0.x, c0.y, ah.q.x, al.q.x);
        split2(c0.z, c0.w, ah.q.y, al.q.y);
        split2(c1.x, c1.y, ah.q.z, al.q.z);
        split2(c1.z, c1.w, ah.q.w, al.q.w);

        acc[0] = __builtin_amdgcn_mfma_f32_16x16x32_bf16(bh0.v, ah.v, acc[0], 0, 0, 0);
        acc[1] = __builtin_amdgcn_mfma_f32_16x16x32_bf16(bh1.v, ah.v, acc[1], 0, 0, 0);
        acc[2] = __builtin_amdgcn_mfma_f32_16x16x32_bf16(bh2.v, ah.v, acc[2], 0, 0, 0);
        acc[3] = __builtin_amdgcn_mfma_f32_16x16x32_bf16(bh3.v, ah.v, acc[3], 0, 0, 0);
        acc[0] = __builtin_amdgcn_mfma_f32_16x16x32_bf16(bl0.v, ah.v, acc[0], 0, 0, 0);
        acc[1] = __builtin_amdgcn_mfma_f32_16x16x32_bf16(bl1.v, ah.v, acc[1], 0, 0, 0);
        acc[2] = __builtin_amdgcn_mfma_f32_16x16x32_bf16(bl2.v, ah.v, acc[2], 0, 0, 0);
        acc[3] = __builtin_amdgcn_mfma_f32_16x16x32_bf16(bl3.v, ah.v, acc[3], 0, 0, 0);
        acc[0] = __builtin_amdgcn_mfma_f32_16x16x32_bf16(bh0.v, al.v, acc[0], 0, 0, 0);
        acc[1] = __builtin_amdgcn_mfma_f32_16x16x32_bf16(bh1.v, al.v, acc[1], 0, 0, 0);
        acc[2] = __builtin_amdgcn_mfma_f32_16x16x32_bf16(bh2.v, al.v, acc[2], 0, 0, 0);
        acc[3] = __builtin_amdgcn_mfma_f32_16x16x32_bf16(bh3.v, al.v, acc[3], 0, 0, 0);

        c0 = p0; c1 = p1;
    }

    if (grow < n) {
#pragma unroll
        for (int t = 0; t < 4; ++t) {
            uint2 p;
            p.x = f2b2(acc[t][0], acc[t][1]);
            p.y = f2b2(acc[t][2], acc[t][3]);
            *(uint2*)(C + (size_t)grow * HDIM + t * 16 + kg * 4) = p;
        }
    }
}

// ---------------- pass B: degree + scan + counting sort; emits rng=(e0,e1,dis) --------
__global__ __launch_bounds__(256) void k_csr(const int* __restrict__ stage,
                                             const int* __restrict__ bcnt,
                                             float* __restrict__ dis,
                                             int4* __restrict__ rng,
                                             int* __restrict__ eadj, int n) {
    __shared__ int cnt[128];
    __shared__ int loc[128];
    __shared__ int lcur[128];
    __shared__ int ebuf[SCAP];   // 16 KB
    const int b = blockIdx.x;
    const int tid = threadIdx.x;
    const int n0 = b << BSHIFT;
    const int nn = min(128, n - n0);
    const int sb = b * SCAP;
    const int len = min(bcnt[b], SCAP);
    if (tid < 128) cnt[tid] = 0;
    __syncthreads();
    for (int j = tid; j < len; j += 256) atomicAdd(&cnt[stage[sb + j] & 127], 1);
    __syncthreads();
    if (tid < 128) loc[tid] = cnt[tid];
    __syncthreads();
    for (int d = 1; d < 128; d <<= 1) {       // Hillis-Steele inclusive scan
        int x = 0;
        if (tid < 128 && tid >= d) x = loc[tid - d];
        __syncthreads();
        if (tid < 128) loc[tid] += x;
        __syncthreads();
    }
    if (tid < 128) {
        int ex = loc[tid] - cnt[tid];          // exclusive
        if (tid < nn) {
            int dg = cnt[tid];
            float di = rsqrtf((float)(dg + 1));
            dis[n0 + tid] = di;
            rng[n0 + tid] = make_int4(sb + ex, sb + ex + dg, __float_as_int(di), 0);
        }
        lcur[tid] = ex;
    }
    __syncthreads();
    for (int j = tid; j < len; j += 256) {
        int p = stage[sb + j];
        int rk = atomicAdd(&lcur[p & 127], 1);
        ebuf[rk] = p >> BSHIFT;
    }
    __syncthreads();
    for (int j = tid; j < len; j += 256) eadj[sb + j] = ebuf[j];  // linear write
}

// ---------------- fgg1: WEIGHTED gather (unscaled h1) + GEMM(W2) + scaled epilogue ----
__global__ __launch_bounds__(256) void k_fggw(const unsigned short* __restrict__ h,
                                              const int* __restrict__ eadj,
                                              const int4* __restrict__ rng,
                                              const float* __restrict__ dis,
                                              const float* __restrict__ bias,
                                              const uint4* __restrict__ Bf,
                                              unsigned short* __restrict__ out, int n) {
    __shared__ uint4 rl[32 * 8];   // 32 rows x 8 uint4 (bf16x8), XOR-swizzled, 4 KB
    const int tid = threadIdx.x;
    const int i0 = blockIdx.x * 32;
    const int node = tid >> 3;
    const int l8 = tid & 7;
    const int i = i0 + node;
    uint4 o = make_uint4(0u, 0u, 0u, 0u);
    if (i < n) {
        const int q = l8 * 8;
        const int4 r = rng[i];
        int e = r.x; const int e1 = r.y;
        const float di = __int_as_float(r.z);
        float a0 = 0.f, a1 = 0.f, a2 = 0.f, a3 = 0.f, a4 = 0.f, a5 = 0.f, a6 = 0.f, a7 = 0.f;
        float g0 = 0.f, g1 = 0.f, g2 = 0.f, g3 = 0.f, g4 = 0.f, g5 = 0.f, g6 = 0.f, g7 = 0.f;
#pragma unroll 2
        for (; e + 3 < e1; e += 4) {
            int s0 = eadj[e];
            int s1 = eadj[e + 1];
            int s2 = eadj[e + 2];
            int s3 = eadj[e + 3];
            uint4 u0 = *(const uint4*)(h + (size_t)s0 * HDIM + q);
            uint4 u1 = *(const uint4*)(h + (size_t)s1 * HDIM + q);
            uint4 u2 = *(const uint4*)(h + (size_t)s2 * HDIM + q);
            uint4 u3 = *(const uint4*)(h + (size_t)s3 * HDIM + q);
            float w0 = dis[s0] * di;
            float w1 = dis[s1] * di;
            float w2 = dis[s2] * di;
            float w3 = dis[s3] * di;
            FMA8(a, u0, w0)
            FMA8(g, u1, w1)
            FMA8(a, u2, w2)
            FMA8(g, u3, w3)
        }
        for (; e < e1; ++e) {
            int s0 = eadj[e];
            uint4 u0 = *(const uint4*)(h + (size_t)s0 * HDIM + q);
            float w0 = dis[s0] * di;
            FMA8(a, u0, w0)
        }
        uint4 us = *(const uint4*)(h + (size_t)i * HDIM + q);   // self, weight di^2
        float sn = di * di;
        FMA8(a, us, sn)
        a0 += g0; a1 += g1; a2 += g2; a3 += g3;
        a4 += g4; a5 += g5; a6 += g6; a7 += g7;
        float4 bl = *(const float4*)(bias + q);
        float4 bh = *(const float4*)(bias + q + 4);
        a0 = fmaxf(a0 + bl.x, 0.f); a1 = fmaxf(a1 + bl.y, 0.f);
        a2 = fmaxf(a2 + bl.z, 0.f); a3 = fmaxf(a3 + bl.w, 0.f);
        a4 = fmaxf(a4 + bh.x, 0.f); a5 = fmaxf(a5 + bh.y, 0.f);
        a6 = fmaxf(a6 + bh.z, 0.f); a7 = fmaxf(a7 + bh.w, 0.f);
        o.x = f2b2(a0, a1); o.y = f2b2(a2, a3);
        o.z = f2b2(a4, a5); o.w = f2b2(a6, a7);
    }
    rl[node * 8 + (l8 ^ (node & 7))] = o;
    __syncthreads();

    const int ln = tid & 63;
    const int wv = tid >> 6;
    const int m  = ln & 15;
    const int kg = ln >> 4;
    const int row = (wv >> 1) * 16 + m;
    const int ct0 = (wv & 1) * 2;
    f32x4v acc0, acc1;
#pragma unroll
    for (int j = 0; j < 4; ++j) { acc0[j] = 0.f; acc1[j] = 0.f; }
#pragma unroll
    for (int ks = 0; ks < 2; ++ks) {
        B8U af;
        af.q = rl[row * 8 + ((ks * 4 + kg) ^ (row & 7))];
        const uint4* bp = Bf + ks * 256 + ln;
        const uint4* bq = Bf + (2 + ks) * 256 + ln;
        B8U bh0, bh1, bl0, bl1;
        bh0.q = bp[ct0 * 64]; bh1.q = bp[(ct0 + 1) * 64];
        bl0.q = bq[ct0 * 64]; bl1.q = bq[(ct0 + 1) * 64];
        acc0 = __builtin_amdgcn_mfma_f32_16x16x32_bf16(bh0.v, af.v, acc0, 0, 0, 0);
        acc1 = __builtin_amdgcn_mfma_f32_16x16x32_bf16(bh1.v, af.v, acc1, 0, 0, 0);
        acc0 = __builtin_amdgcn_mfma_f32_16x16x32_bf16(bl0.v, af.v, acc0, 0, 0, 0);
        acc1 = __builtin_amdgcn_mfma_f32_16x16x32_bf16(bl1.v, af.v, acc1, 0, 0, 0);
    }
    const int grow = i0 + row;
    if (grow < n) {
        const float di = dis[grow];
        uint2 p;
        p.x = f2b2(acc0[0] * di, acc0[1] * di);
        p.y = f2b2(acc0[2] * di, acc0[3] * di);
        *(uint2*)(out + (size_t)grow * HDIM + ct0 * 16 + kg * 4) = p;
        p.x = f2b2(acc1[0] * di, acc1[1] * di);
        p.y = f2b2(acc1[2] * di, acc1[3] * di);
        *(uint2*)(out + (size_t)grow * HDIM + (ct0 + 1) * 16 + kg * 4) = p;
    }
}

// ---------------- fgg2: pure-add gather (pre-scaled h) + GEMM(W3) + scaled epilogue ---
__global__ __launch_bounds__(256) void k_fgg(const unsigned short* __restrict__ h,
                                             const int* __restrict__ eadj,
                                             const int4* __restrict__ rng,
                                             const float* __restrict__ bias,
                                             const uint4* __restrict__ Bf,
                                             const float* __restrict__ dis,
                                             unsigned short* __restrict__ out, int n) {
    __shared__ uint4 rl[32 * 8];
    const int tid = threadIdx.x;
    const int i0 = blockIdx.x * 32;
    const int node = tid >> 3;
    const int l8 = tid & 7;
    const int i = i0 + node;
    uint4 o = make_uint4(0u, 0u, 0u, 0u);
    if (i < n) {
        const int q = l8 * 8;
        const int4 r = rng[i];
        int e = r.x; const int e1 = r.y;
        const float di = __int_as_float(r.z);
        float a0 = 0.f, a1 = 0.f, a2 = 0.f, a3 = 0.f, a4 = 0.f, a5 = 0.f, a6 = 0.f, a7 = 0.f;
        float g0 = 0.f, g1 = 0.f, g2 = 0.f, g3 = 0.f, g4 = 0.f, g5 = 0.f, g6 = 0.f, g7 = 0.f;
#pragma unroll 2
        for (; e + 3 < e1; e += 4) {
            int s0 = eadj[e];
            int s1 = eadj[e + 1];
            int s2 = eadj[e + 2];
            int s3 = eadj[e + 3];
            uint4 u0 = *(const uint4*)(h + (size_t)s0 * HDIM + q);
            uint4 u1 = *(const uint4*)(h + (size_t)s1 * HDIM + q);
            uint4 u2 = *(const uint4*)(h + (size_t)s2 * HDIM + q);
            uint4 u3 = *(const uint4*)(h + (size_t)s3 * HDIM + q);
            ADD8(a, u0)
            ADD8(g, u1)
            ADD8(a, u2)
            ADD8(g, u3)
        }
        for (; e < e1; ++e) {
            int s0 = eadj[e];
            uint4 u0 = *(const uint4*)(h + (size_t)s0 * HDIM + q);
            ADD8(a, u0)
        }
        uint4 us = *(const uint4*)(h + (size_t)i * HDIM + q);
        ADD8(a, us)
        a0 += g0; a1 += g1; a2 += g2; a3 += g3;
        a4 += g4; a5 += g5; a6 += g6; a7 += g7;
        float4 bl = *(const float4*)(bias + q);
        float4 bh = *(const float4*)(bias + q + 4);
        a0 = fmaxf(fmaf(a0, di, bl.x), 0.f);
        a1 = fmaxf(fmaf(a1, di, bl.y), 0.f);
        a2 = fmaxf(fmaf(a2, di, bl.z), 0.f);
        a3 = fmaxf(fmaf(a3, di, bl.w), 0.f);
        a4 = fmaxf(fmaf(a4, di, bh.x), 0.f);
        a5 = fmaxf(fmaf(a5, di, bh.y), 0.f);
        a6 = fmaxf(fmaf(a6, di, bh.z), 0.f);
        a7 = fmaxf(fmaf(a7, di, bh.w), 0.f);
        o.x = f2b2(a0, a1); o.y = f2b2(a2, a3);
        o.z = f2b2(a4, a5); o.w = f2b2(a6, a7);
    }
    rl[node * 8 + (l8 ^ (node & 7))] = o;
    __syncthreads();

    const int ln = tid & 63;
    const int wv = tid >> 6;
    const int m  = ln & 15;
    const int kg = ln >> 4;
    const int row = (wv >> 1) * 16 + m;
    const int ct0 = (wv & 1) * 2;
    f32x4v acc0, acc1;
#pragma unroll
    for (int j = 0; j < 4; ++j) { acc0[j] = 0.f; acc1[j] = 0.f; }
#pragma unroll
    for (int ks = 0; ks < 2; ++ks) {
        B8U af;
        af.q = rl[row * 8 + ((ks * 4 + kg) ^ (row & 7))];
        const uint4* bp = Bf + ks * 256 + ln;
        const uint4* bq = Bf + (2 + ks) * 256 + ln;
        B8U bh0, bh1, bl0, bl1;
        bh0.q = bp[ct0 * 64]; bh1.q = bp[(ct0 + 1) * 64];
        bl0.q = bq[ct0 * 64]; bl1.q = bq[(ct0 + 1) * 64];
        acc0 = __builtin_amdgcn_mfma_f32_16x16x32_bf16(bh0.v, af.v, acc0, 0, 0, 0);
        acc1 = __builtin_amdgcn_mfma_f32_16x16x32_bf16(bh1.v, af.v, acc1, 0, 0, 0);
        acc0 = __builtin_amdgcn_mfma_f32_16x16x32_bf16(bl0.v, af.v, acc0, 0, 0, 0);
        acc1 = __builtin_amdgcn_mfma_f32_16x16x32_bf16(bl1.v, af.v, acc1, 0, 0, 0);
    }
    const int grow = i0 + row;
    if (grow < n) {
        const float di = dis[grow];
        uint2 p;
        p.x = f2b2(acc0[0] * di, acc0[1] * di);
        p.y = f2b2(acc0[2] * di, acc0[3] * di);
        *(uint2*)(out + (size_t)grow * HDIM + ct0 * 16 + kg * 4) = p;
        p.x = f2b2(acc1[0] * di, acc1[1] * di);
        p.y = f2b2(acc1[2] * di, acc1[3] * di);
        *(uint2*)(out + (size_t)grow * HDIM + (ct0 + 1) * 16 + kg * 4) = p;
    }
}

// ---------------- layer-3 gather fused with mean-pool accumulate ----------------------
__global__ __launch_bounds__(256) void k_gather_pool(const unsigned short* __restrict__ h,
                                                     const int* __restrict__ eadj,
                                                     const int4* __restrict__ rng,
                                                     const float* __restrict__ bias,
                                                     const int* __restrict__ batch,
                                                     float* __restrict__ pooled, int n) {
    __shared__ float sp[NGRAPH][HDIM];   // 16 KB
    const int tid = threadIdx.x;
    int t = blockIdx.x * 256 + tid;
    int i = t >> 3;
    const bool valid = (i < n);
    int q = (t & 7) * 8;
    const int i0 = (blockIdx.x * 256) >> 3;
    const int i1 = min(i0 + 32, n);
    const int gmin = batch[min(i0, n - 1)];
    const int gmax = batch[i1 - 1];
    for (int j = tid; j < NGRAPH * HDIM; j += 256) ((float*)sp)[j] = 0.f;
    __syncthreads();
    if (valid) {
        const int4 r = rng[i];
        int e = r.x; const int e1 = r.y;
        const float di = __int_as_float(r.z);
        float a0 = 0.f, a1 = 0.f, a2 = 0.f, a3 = 0.f, a4 = 0.f, a5 = 0.f, a6 = 0.f, a7 = 0.f;
        float g0 = 0.f, g1 = 0.f, g2 = 0.f, g3 = 0.f, g4 = 0.f, g5 = 0.f, g6 = 0.f, g7 = 0.f;
#pragma unroll 2
        for (; e + 3 < e1; e += 4) {
            int s0 = eadj[e];
            int s1 = eadj[e + 1];
            int s2 = eadj[e + 2];
            int s3 = eadj[e + 3];
            uint4 u0 = *(const uint4*)(h + (size_t)s0 * HDIM + q);
            uint4 u1 = *(const uint4*)(h + (size_t)s1 * HDIM + q);
            uint4 u2 = *(const uint4*)(h + (size_t)s2 * HDIM + q);
            uint4 u3 = *(const uint4*)(h + (size_t)s3 * HDIM + q);
            ADD8(a, u0)
            ADD8(g, u1)
            ADD8(a, u2)
            ADD8(g, u3)
        }
        for (; e < e1; ++e) {
            int s0 = eadj[e];
            uint4 u0 = *(const uint4*)(h + (size_t)s0 * HDIM + q);
            ADD8(a, u0)
        }
        uint4 us = *(const uint4*)(h + (size_t)i * HDIM + q);
        ADD8(a, us)
        a0 += g0; a1 += g1; a2 += g2; a3 += g3;
        a4 += g4; a5 += g5; a6 += g6; a7 += g7;
        float4 bl = *(const float4*)(bias + q);
        float4 bh = *(const float4*)(bias + q + 4);
        a0 = fmaxf(fmaf(a0, di, bl.x), 0.f);
        a1 = fmaxf(fmaf(a1, di, bl.y), 0.f);
        a2 = fmaxf(fmaf(a2, di, bl.z), 0.f);
        a3 = fmaxf(fmaf(a3, di, bl.w), 0.f);
        a4 = fmaxf(fmaf(a4, di, bh.x), 0.f);
        a5 = fmaxf(fmaf(a5, di, bh.y), 0.f);
        a6 = fmaxf(fmaf(a6, di, bh.z), 0.f);
        a7 = fmaxf(fmaf(a7, di, bh.w), 0.f);
        int g = batch[i];
        atomicAdd(&sp[g][q + 0], a0); atomicAdd(&sp[g][q + 1], a1);
        atomicAdd(&sp[g][q + 2], a2); atomicAdd(&sp[g][q + 3], a3);
        atomicAdd(&sp[g][q + 4], a4); atomicAdd(&sp[g][q + 5], a5);
        atomicAdd(&sp[g][q + 6], a6); atomicAdd(&sp[g][q + 7], a7);
    }
    __syncthreads();
    int rows = gmax - gmin + 1;
    for (int j = tid; j < rows * HDIM; j += 256) {
        int r = j >> 6, c = j & 63;
        float v = sp[gmin + r][c];
        if (v != 0.f) atomicAdd(&pooled[(gmin + r) * HDIM + c], v);
    }
}

// ---------------- mean + linear head ----------------
__global__ __launch_bounds__(640) void k_head(const float* __restrict__ pooled,
                                              const int* __restrict__ batch,
                                              const float* __restrict__ linW,
                                              const float* __restrict__ linb,
                                              float* __restrict__ out, int n) {
    int t = threadIdx.x;
    if (t >= NGRAPH * NCLS) return;
    int g = t / NCLS;
    int c = t - g * NCLS;
    int lo = 0, hi = n;
    while (lo < hi) { int m = (lo + hi) >> 1; if (batch[m] < g) lo = m + 1; else hi = m; }
    int s = lo;
    lo = 0; hi = n;
    while (lo < hi) { int m = (lo + hi) >> 1; if (batch[m] < g + 1) lo = m + 1; else hi = m; }
    float inv = 1.0f / fmaxf((float)(lo - s), 1.0f);
    float acc = linb[c];
#pragma unroll
    for (int k = 0; k < HDIM; ++k)
        acc = fmaf(pooled[g * HDIM + k] * inv, linW[k * NCLS + c], acc);
    out[g * NCLS + c] = acc;
}

extern "C" void kernel_launch(void* const* d_in, const int* in_sizes, int n_in,
                              void* d_out, int out_size, void* d_ws, size_t ws_size,
                              hipStream_t stream) {
    (void)in_sizes; (void)n_in; (void)out_size; (void)ws_size;
    const float* x    = (const float*)d_in[0];
    const int*   ei   = (const int*)d_in[1];
    const int*   batch= (const int*)d_in[2];
    const float* W1   = (const float*)d_in[3];
    const float* b1   = (const float*)d_in[4];
    const float* W2   = (const float*)d_in[5];
    const float* b2   = (const float*)d_in[6];
    const float* W3   = (const float*)d_in[7];
    const float* b3   = (const float*)d_in[8];
    const float* linW = (const float*)d_in[9];
    const float* linb = (const float*)d_in[10];
    float* out = (float*)d_out;

    const int N = N_NODES, E = N_EDGES;
    const int* src = ei;
    const int* dst = ei + E;

    char* ws = (char*)d_ws;
    unsigned short* hA = (unsigned short*)ws; ws += (size_t)N * HDIM * 2;
    unsigned short* hB = (unsigned short*)ws; ws += (size_t)N * HDIM * 2;
    float* dis    = (float*)ws; ws += (size_t)N * 4;
    int*   eadj   = (int*)ws;   ws += (size_t)NBUCK * SCAP * 4;
    int*   stage  = (int*)ws;   ws += (size_t)NBUCK * SCAP * 4;
    int4*  rng    = (int4*)ws;  ws += (size_t)N * 16;
    int*   bcnt   = (int*)ws;   ws += ((size_t)NBUCK * 4 + 15) & ~(size_t)15;
    float* pooled = (float*)ws; ws += (size_t)NGRAPH * HDIM * 4;
    uint4* Bf1    = (uint4*)ws; ws += (size_t)2 * 8 * 4 * 64 * 16;   // 64 KB
    uint4* Bf2    = (uint4*)ws; ws += (size_t)2 * 2 * 4 * 64 * 16;   // 16 KB
    uint4* Bf3    = (uint4*)ws; ws += (size_t)2 * 2 * 4 * 64 * 16;   // 16 KB

    const int gb  = (N + 63) / 64;        // 782
    const int nF  = (N + 31) / 32;        // 1563

    k_prepZ<<<12, 256, 0, stream>>>(W1, W2, W3, Bf1, Bf2, Bf3, bcnt, pooled);
    // edge partition ∪ layer-1 GEMM (independent: gemm does not need dis)
    k_pg<<<PARTB + gb, 256, 0, stream>>>(src, dst, bcnt, stage, E,
                                         x, Bf1, hA, N, F_INPUT, 8);
    k_csr<<<NBUCK, 256, 0, stream>>>(stage, bcnt, dis, rng, eadj, N);
    // layer-1 gather (weighted, unscaled h1) + layer-2 GEMM, pre-scaled output
    k_fggw<<<nF, 256, 0, stream>>>(hA, eadj, rng, dis, b1, Bf2, hB, N);
    // layer-2 gather (pure add) + layer-3 GEMM, pre-scaled output
    k_fgg<<<nF, 256, 0, stream>>>(hB, eadj, rng, b2, Bf3, dis, hA, N);
    // layer-3 gather + pool
    k_gather_pool<<<nF, 256, 0, stream>>>(hA, eadj, rng, b3, batch, pooled, N);
    // head
    k_head<<<1, 640, 0, stream>>>(pooled, batch, linW, linb, out, N);
}